// Round 27
// baseline (184.333 us; speedup 1.0000x reference)
//
#include <hip/hip_runtime.h>

#define B_   128
#define L_   196
#define ENC_ 2048
#define DEC_ 512
#define ATT_ 512
#define M_   (B_ * L_)   // 25088

typedef _Float16 f16x4 __attribute__((ext_vector_type(4)));
typedef _Float16 f16x8 __attribute__((ext_vector_type(8)));
typedef __fp16   h16x2 __attribute__((ext_vector_type(2)));
typedef float    f32x4 __attribute__((ext_vector_type(4)));

// Raw barrier: order LDS ops (lgkmcnt) but do NOT drain vmcnt -> global
// prefetches stay in flight across the barrier.
#define FENCE_LDS_BARRIER()                                        \
    do {                                                           \
        asm volatile("s_waitcnt lgkmcnt(0)" ::: "memory");         \
        __builtin_amdgcn_s_barrier();                              \
        __builtin_amdgcn_sched_barrier(0);                         \
    } while (0)

// ---------------- ws layout ----------------
// [0,        262144)   dec_map f32 [128][512]
// [262144,  2359296)   WeTs    f16 tiled [nt=4][kt=64][k8=4][row=128] x f16x8
// [2359296, 2760704)   partial f32 [4][25088]
// [4194304, 20971520)  tailbuf f32 [256][16384]  (16 tail tiles x 16 K-chunks)

__global__ void wets_kernel(const float* __restrict__ We, _Float16* __restrict__ WeTs) {
    int u = blockIdx.x * 256 + threadIdx.x;     // 131072 units
    int row = u & 127;
    int k8  = (u >> 7) & 3;
    int kt  = (u >> 9) & 63;
    int nt  = u >> 15;
    int n  = nt * 128 + row;
    int k0 = kt * 32 + k8 * 8;
    f16x8 h;
#pragma unroll
    for (int j = 0; j < 8; ++j) h[j] = (_Float16)We[(k0 + j) * ATT_ + n];
    *reinterpret_cast<f16x8*>(WeTs + (size_t)u * 8) = h;
}

__global__ void decmap_kernel(const float* __restrict__ dh, const float* __restrict__ Wd,
                              const float* __restrict__ bd, float* __restrict__ dec) {
    int b = blockIdx.x;       // 128
    int a = threadIdx.x;      // 512
    float acc = bd[a];
    const float* dhp = dh + b * DEC_;
#pragma unroll 8
    for (int k = 0; k < DEC_; ++k) acc += dhp[k] * Wd[k * ATT_ + a];
    dec[b * ATT_ + a] = acc;
}

// ---------- shared GEMM machinery (R8's measured-best 128x128 pipeline) ----
// A: fp32->f16 reg staging, 2 static sets, swizzled LDS dbuf; B: reg-staged
// f16 from pre-tiled WeTs; lgkm-only barriers (no vmcnt drain). (256,3).

#define GEMM_PRELUDE(MTILE, NTILE)                                           \
    __shared__ _Float16 smem[2][2][4096];                                    \
    __shared__ float red[2][128];                                            \
    int tid  = threadIdx.x;                                                  \
    int lane = tid & 63, wid = tid >> 6;                                     \
    int wm = wid >> 1, wn = wid & 1;                                         \
    int l15 = lane & 15, lg = lane >> 4;                                     \
    int arowi = tid >> 2;                                                    \
    int ac8   = tid & 3;                                                     \
    const float* agA = enc + (size_t)((MTILE) * 128 + arowi) * ENC_ + ac8 * 8; \
    const float* agB = agA + (size_t)64 * ENC_;                              \
    int wa0 = (ac8 * 128 + (arowi ^ (2 * ac8))) * 8;                         \
    int wa1 = wa0 + 64 * 8;                                                  \
    const _Float16* bbase = WeTs + (size_t)(NTILE) * 64 * 4096;              \
    int afo = (lg * 128 + wm * 64 + (l15 ^ (2 * lg))) * 8;                   \
    int bfo = (lg * 128 + wn * 64 + l15) * 8;                                \
    float4 areg0[4], areg1[4];                                               \
    f16x8  breg0[2], breg1[2];                                               \
    f32x4 acc[4][4];                                                         \
    _Pragma("unroll")                                                        \
    for (int mi = 0; mi < 4; ++mi)                                           \
        _Pragma("unroll")                                                    \
        for (int ni = 0; ni < 4; ++ni) acc[mi][ni] = (f32x4){0.f, 0.f, 0.f, 0.f}; \
    auto load0 = [&](int kt) {                                               \
        const float* a0 = agA + kt * 32;                                     \
        const float* a1 = agB + kt * 32;                                     \
        areg0[0] = *reinterpret_cast<const float4*>(a0);                     \
        areg0[1] = *reinterpret_cast<const float4*>(a0 + 4);                 \
        areg0[2] = *reinterpret_cast<const float4*>(a1);                     \
        areg0[3] = *reinterpret_cast<const float4*>(a1 + 4);                 \
        const _Float16* bs = bbase + (size_t)kt * 4096;                      \
        breg0[0] = *reinterpret_cast<const f16x8*>(bs + tid * 8);            \
        breg0[1] = *reinterpret_cast<const f16x8*>(bs + (tid + 256) * 8);    \
    };                                                                       \
    auto load1 = [&](int kt) {                                               \
        const float* a0 = agA + kt * 32;                                     \
        const float* a1 = agB + kt * 32;                                     \
        areg1[0] = *reinterpret_cast<const float4*>(a0);                     \
        areg1[1] = *reinterpret_cast<const float4*>(a0 + 4);                 \
        areg1[2] = *reinterpret_cast<const float4*>(a1);                     \
        areg1[3] = *reinterpret_cast<const float4*>(a1 + 4);                 \
        const _Float16* bs = bbase + (size_t)kt * 4096;                      \
        breg1[0] = *reinterpret_cast<const f16x8*>(bs + tid * 8);            \
        breg1[1] = *reinterpret_cast<const f16x8*>(bs + (tid + 256) * 8);    \
    };                                                                       \
    auto write0 = [&](int buf) {                                             \
        _Float16* As = smem[buf][0];                                         \
        _Float16* Bsl = smem[buf][1];                                        \
        union { h16x2 h2[4]; f16x8 h8; } cv;                                 \
        cv.h2[0] = __builtin_amdgcn_cvt_pkrtz(areg0[0].x, areg0[0].y);       \
        cv.h2[1] = __builtin_amdgcn_cvt_pkrtz(areg0[0].z, areg0[0].w);       \
        cv.h2[2] = __builtin_amdgcn_cvt_pkrtz(areg0[1].x, areg0[1].y);       \
        cv.h2[3] = __builtin_amdgcn_cvt_pkrtz(areg0[1].z, areg0[1].w);       \
        *reinterpret_cast<f16x8*>(As + wa0) = cv.h8;                         \
        cv.h2[0] = __builtin_amdgcn_cvt_pkrtz(areg0[2].x, areg0[2].y);       \
        cv.h2[1] = __builtin_amdgcn_cvt_pkrtz(areg0[2].z, areg0[2].w);       \
        cv.h2[2] = __builtin_amdgcn_cvt_pkrtz(areg0[3].x, areg0[3].y);       \
        cv.h2[3] = __builtin_amdgcn_cvt_pkrtz(areg0[3].z, areg0[3].w);       \
        *reinterpret_cast<f16x8*>(As + wa1) = cv.h8;                         \
        *reinterpret_cast<f16x8*>(Bsl + tid * 8) = breg0[0];                 \
        *reinterpret_cast<f16x8*>(Bsl + (tid + 256) * 8) = breg0[1];         \
    };                                                                       \
    auto write1 = [&](int buf) {                                             \
        _Float16* As = smem[buf][0];                                         \
        _Float16* Bsl = smem[buf][1];                                        \
        union { h16x2 h2[4]; f16x8 h8; } cv;                                 \
        cv.h2[0] = __builtin_amdgcn_cvt_pkrtz(areg1[0].x, areg1[0].y);       \
        cv.h2[1] = __builtin_amdgcn_cvt_pkrtz(areg1[0].z, areg1[0].w);       \
        cv.h2[2] = __builtin_amdgcn_cvt_pkrtz(areg1[1].x, areg1[1].y);       \
        cv.h2[3] = __builtin_amdgcn_cvt_pkrtz(areg1[1].z, areg1[1].w);       \
        *reinterpret_cast<f16x8*>(As + wa0) = cv.h8;                         \
        cv.h2[0] = __builtin_amdgcn_cvt_pkrtz(areg1[2].x, areg1[2].y);       \
        cv.h2[1] = __builtin_amdgcn_cvt_pkrtz(areg1[2].z, areg1[2].w);       \
        cv.h2[2] = __builtin_amdgcn_cvt_pkrtz(areg1[3].x, areg1[3].y);       \
        cv.h2[3] = __builtin_amdgcn_cvt_pkrtz(areg1[3].z, areg1[3].w);       \
        *reinterpret_cast<f16x8*>(As + wa1) = cv.h8;                         \
        *reinterpret_cast<f16x8*>(Bsl + tid * 8) = breg1[0];                 \
        *reinterpret_cast<f16x8*>(Bsl + (tid + 256) * 8) = breg1[1];         \
    };                                                                       \
    auto compute = [&](const _Float16* As, const _Float16* Bsl) {            \
        f16x8 af[4], bf[4];                                                  \
        _Pragma("unroll")                                                    \
        for (int mi = 0; mi < 4; ++mi)                                       \
            af[mi] = *reinterpret_cast<const f16x8*>(As + afo + mi * 128);   \
        _Pragma("unroll")                                                    \
        for (int ni = 0; ni < 4; ++ni)                                       \
            bf[ni] = *reinterpret_cast<const f16x8*>(Bsl + bfo + ni * 128);  \
        _Pragma("unroll")                                                    \
        for (int mi = 0; mi < 4; ++mi)                                       \
            _Pragma("unroll")                                                \
            for (int ni = 0; ni < 4; ++ni)                                   \
                acc[mi][ni] = __builtin_amdgcn_mfma_f32_16x16x32_f16(        \
                    af[mi], bf[ni], acc[mi][ni], 0, 0, 0);                   \
    };

// Shared fused epilogue: x = acc + be + dec; rowsum += tanh(x)*wa; reduce.
#define GEMM_EPILOGUE(MTILE, NTILE)                                          \
    do {                                                                     \
        float rsum[4][4];                                                    \
        _Pragma("unroll")                                                    \
        for (int mi = 0; mi < 4; ++mi)                                       \
            _Pragma("unroll")                                                \
            for (int j = 0; j < 4; ++j) rsum[mi][j] = 0.f;                   \
        int nb = (NTILE) * 128 + wn * 64;                                    \
        int rb = (MTILE) * 128 + wm * 64;                                    \
        _Pragma("unroll")                                                    \
        for (int ni = 0; ni < 4; ++ni) {                                     \
            int n = nb + ni * 16 + l15;                                      \
            float wav = wa[n];                                               \
            float bev = be[n];                                               \
            _Pragma("unroll")                                                \
            for (int mi = 0; mi < 4; ++mi) {                                 \
                _Pragma("unroll")                                            \
                for (int j = 0; j < 4; ++j) {                                \
                    int row = rb + mi * 16 + lg * 4 + j;                     \
                    int b = row / L_;                                        \
                    float x = acc[mi][ni][j] + bev + dec[b * ATT_ + n];      \
                    float e = __expf(2.0f * x);                              \
                    float t = 1.0f - 2.0f / (e + 1.0f);                      \
                    rsum[mi][j] += t * wav;                                  \
                }                                                            \
            }                                                                \
        }                                                                    \
        _Pragma("unroll")                                                    \
        for (int mi = 0; mi < 4; ++mi) {                                     \
            _Pragma("unroll")                                                \
            for (int j = 0; j < 4; ++j) {                                    \
                float v = rsum[mi][j];                                       \
                v += __shfl_xor(v, 1);                                       \
                v += __shfl_xor(v, 2);                                       \
                v += __shfl_xor(v, 4);                                       \
                v += __shfl_xor(v, 8);                                       \
                if (l15 == 0) red[wn][wm * 64 + mi * 16 + lg * 4 + j] = v;   \
            }                                                                \
        }                                                                    \
        __syncthreads();                                                     \
        if (tid < 128)                                                       \
            partial[(size_t)(NTILE) * M_ + (MTILE) * 128 + tid] =            \
                red[0][tid] + red[1][tid];                                   \
    } while (0)

// Main GEMM: 768 blocks = mtiles 0..191 x 4 ntiles. Exactly 3 blocks/CU x
// 256 CUs -> SINGLE fully-overlapped round (R8's measured ~63us/round).
__global__ __launch_bounds__(256, 3)
void gemm_main_kernel(const float* __restrict__ enc,
                      const _Float16* __restrict__ WeTs,
                      const float* __restrict__ be,
                      const float* __restrict__ wa,
                      const float* __restrict__ dec,
                      float* __restrict__ partial) {
    int bid = blockIdx.x;
    int sid = (bid & 7) * 96 + (bid >> 3);           // 768 = 8*96, bijective
    int mtile = sid >> 2;                            // 0..191
    int ntile = sid & 3;

    GEMM_PRELUDE(mtile, ntile)

    load0(0);
    load1(1);
    write0(0);
    FENCE_LDS_BARRIER();
    for (int kt2 = 0; kt2 < 32; ++kt2) {
        int kt = kt2 * 2;
        if (kt2 < 31) load0(kt + 2);
        compute(smem[0][0], smem[0][1]);
        write1(1);
        FENCE_LDS_BARRIER();
        if (kt2 < 31) load1(kt + 3);
        compute(smem[1][0], smem[1][1]);
        if (kt2 < 31) write0(0);
        FENCE_LDS_BARRIER();
    }

    GEMM_EPILOGUE(mtile, ntile);
}

// Tail GEMM: the 16 leftover tiles (mtiles 192..195 x 4 ntiles), each K-split
// 16 ways (K-chunk = 128 = 4 BK-steps) -> 256 short blocks (~4 phases).
// Writes RAW accumulators (tanh is nonlinear; K-partials summed in fixup).
__global__ __launch_bounds__(256, 3)
void gemm_tail_kernel(const float* __restrict__ enc,
                      const _Float16* __restrict__ WeTs,
                      float* __restrict__ tailbuf) {
    int idx = blockIdx.x;                            // 0..255
    int t   = idx >> 4;                              // 0..15 tile
    int kc  = idx & 15;                              // K-chunk
    int mtile = 192 + (t >> 2);
    int ntile = t & 3;
    int k0 = kc * 4;                                 // BK-step base

    GEMM_PRELUDE(mtile, ntile)

    load0(k0);
    load1(k0 + 1);
    write0(0);
    FENCE_LDS_BARRIER();
    for (int kt2 = 0; kt2 < 2; ++kt2) {
        int kt = k0 + kt2 * 2;
        if (kt2 < 1) load0(kt + 2);
        compute(smem[0][0], smem[0][1]);
        write1(1);
        FENCE_LDS_BARRIER();
        if (kt2 < 1) load1(kt + 3);
        compute(smem[1][0], smem[1][1]);
        if (kt2 < 1) write0(0);
        FENCE_LDS_BARRIER();
    }

    // raw accumulator dump: thread-major, fragment order (16 x f32x4)
    float* out = tailbuf + (size_t)idx * 16384 + tid * 64;
#pragma unroll
    for (int mi = 0; mi < 4; ++mi)
#pragma unroll
        for (int ni = 0; ni < 4; ++ni)
            *reinterpret_cast<f32x4*>(out + (mi * 4 + ni) * 4) = acc[mi][ni];
}

// Fixup: per tail tile, sum the 16 K-chunk partials (same thread<->fragment
// mapping as the tail blocks) and run the stock epilogue.
__global__ __launch_bounds__(256, 2)
void fixup_kernel(const float* __restrict__ tailbuf,
                  const float* __restrict__ be,
                  const float* __restrict__ wa,
                  const float* __restrict__ dec,
                  float* __restrict__ partial) {
    __shared__ float red[2][128];
    int t = blockIdx.x;                              // 0..15
    int mtile = 192 + (t >> 2);
    int ntile = t & 3;

    int tid  = threadIdx.x;
    int lane = tid & 63, wid = tid >> 6;
    int wm = wid >> 1, wn = wid & 1;
    int l15 = lane & 15, lg = lane >> 4;

    f32x4 acc[4][4];
#pragma unroll
    for (int mi = 0; mi < 4; ++mi)
#pragma unroll
        for (int ni = 0; ni < 4; ++ni) acc[mi][ni] = (f32x4){0.f, 0.f, 0.f, 0.f};

    const float* base = tailbuf + (size_t)(t * 16) * 16384 + tid * 64;
#pragma unroll 4
    for (int c = 0; c < 16; ++c) {
        const float* p = base + (size_t)c * 16384;
#pragma unroll
        for (int mi = 0; mi < 4; ++mi)
#pragma unroll
            for (int ni = 0; ni < 4; ++ni) {
                f32x4 v = *reinterpret_cast<const f32x4*>(p + (mi * 4 + ni) * 4);
                acc[mi][ni] += v;
            }
    }

    GEMM_EPILOGUE(mtile, ntile);
}

// softmax over L per batch row; sums the 4 ntile partials. ba cancels.
__global__ void softmax_kernel(const float* __restrict__ partial, float* __restrict__ alphas) {
    int b = blockIdx.x, t = threadIdx.x;     // 128 blocks x 256 threads
    int lane = t & 63, wid = t >> 6;
    __shared__ float red[4];
    float s = 0.f, val = -1e30f;
    if (t < L_) {
        int r = b * L_ + t;
        s = partial[r] + partial[M_ + r] + partial[2 * M_ + r] + partial[3 * M_ + r];
        val = s;
    }
    float m = val;
#pragma unroll
    for (int off = 1; off < 64; off <<= 1) m = fmaxf(m, __shfl_xor(m, off));
    if (lane == 0) red[wid] = m;
    __syncthreads();
    m = fmaxf(fmaxf(red[0], red[1]), fmaxf(red[2], red[3]));
    float e = (t < L_) ? __expf(s - m) : 0.f;
    float sum = e;
#pragma unroll
    for (int off = 1; off < 64; off <<= 1) sum += __shfl_xor(sum, off);
    __syncthreads();
    if (lane == 0) red[wid] = sum;
    __syncthreads();
    sum = red[0] + red[1] + red[2] + red[3];
    if (t < L_) alphas[b * L_ + t] = e / sum;
}

// context[b][e] = sum_l alphas[b][l] * enc[b][l][e]  (float4 loads, G13)
__global__ void context_kernel(const float* __restrict__ enc, const float* __restrict__ alphas,
                               float* __restrict__ ctx) {
    int b = blockIdx.x >> 1;                  // 128 b x 2 e-chunks = 256 blocks
    int ec = blockIdx.x & 1;
    int e = ec * 1024 + threadIdx.x * 4;
    const float* ep = enc + (size_t)b * L_ * ENC_ + e;
    const float* ap = alphas + b * L_;
    float a0 = 0.f, a1 = 0.f, a2 = 0.f, a3 = 0.f;
#pragma unroll 4
    for (int l = 0; l < L_; ++l) {
        float a = ap[l];
        float4 v = *reinterpret_cast<const float4*>(ep + (size_t)l * ENC_);
        a0 += a * v.x;
        a1 += a * v.y;
        a2 += a * v.z;
        a3 += a * v.w;
    }
    float4 r; r.x = a0; r.y = a1; r.z = a2; r.w = a3;
    *reinterpret_cast<float4*>(&ctx[b * ENC_ + e]) = r;
}

extern "C" void kernel_launch(void* const* d_in, const int* in_sizes, int n_in,
                              void* d_out, int out_size, void* d_ws, size_t ws_size,
                              hipStream_t stream) {
    const float* enc = (const float*)d_in[0];
    const float* dh  = (const float*)d_in[1];
    const float* We  = (const float*)d_in[2];
    const float* be  = (const float*)d_in[3];
    const float* Wd  = (const float*)d_in[4];
    const float* bd  = (const float*)d_in[5];
    const float* wa  = (const float*)d_in[6];
    // d_in[7] = ba: shifts all scores equally -> cancels in softmax, unused.

    float* out    = (float*)d_out;
    float* ctx    = out;               // [128][2048]
    float* alphas = out + B_ * ENC_;   // [128][196]

    char* ws = (char*)d_ws;
    float*    dec     = (float*)ws;                            // 256 KiB
    _Float16* WeTs    = (_Float16*)(ws + 262144);              // 2 MiB
    float*    partial = (float*)(ws + 2359296);                // 392 KiB
    float*    tailbuf = (float*)(ws + 4194304);                // 16 MiB

    hipLaunchKernelGGL(wets_kernel,      dim3(512), dim3(256), 0, stream, We, WeTs);
    hipLaunchKernelGGL(decmap_kernel,    dim3(128), dim3(512), 0, stream, dh, Wd, bd, dec);
    hipLaunchKernelGGL(gemm_main_kernel, dim3(768), dim3(256), 0, stream, enc, WeTs, be, wa, dec, partial);
    hipLaunchKernelGGL(gemm_tail_kernel, dim3(256), dim3(256), 0, stream, enc, WeTs, tailbuf);
    hipLaunchKernelGGL(fixup_kernel,     dim3(16),  dim3(256), 0, stream, tailbuf, be, wa, dec, partial);
    hipLaunchKernelGGL(softmax_kernel,   dim3(128), dim3(256), 0, stream, partial, alphas);
    hipLaunchKernelGGL(context_kernel,   dim3(256), dim3(256), 0, stream, enc, alphas, ctx);
}

// Round 28
// 140.946 us; speedup vs baseline: 1.3078x; 1.3078x over previous
//
#include <hip/hip_runtime.h>

#define B_   128
#define L_   196
#define ENC_ 2048
#define DEC_ 512
#define ATT_ 512
#define M_   (B_ * L_)   // 25088

typedef _Float16 f16x8 __attribute__((ext_vector_type(8)));
typedef __fp16   h16x2 __attribute__((ext_vector_type(2)));
typedef float    f32x4 __attribute__((ext_vector_type(4)));

// Raw barrier: order LDS ops (lgkmcnt) but do NOT drain vmcnt.
#define FENCE_LDS_BARRIER()                                        \
    do {                                                           \
        asm volatile("s_waitcnt lgkmcnt(0)" ::: "memory");         \
        __builtin_amdgcn_s_barrier();                              \
        __builtin_amdgcn_sched_barrier(0);                         \
    } while (0)

__device__ __forceinline__ void gload16(const _Float16* g, _Float16* l) {
    __builtin_amdgcn_global_load_lds(
        (const __attribute__((address_space(1))) void*)g,
        (__attribute__((address_space(3))) void*)l, 16, 0, 0);
}

// ---------------- ws layout ----------------
// [0,        262144)  dec_map f32 [128][512]
// [262144,  2359296)  WeTs2   f16 tiled [nt2=2][kt=64][k8=4][col=256] x f16x8
// [2359296, 2559904)  scores  f32 [2][25088]

// We [2048][512] fp32 -> WeTs2 tiled f16. Unit (nt2,kt,k8,col) holds
// We[kt*32+k8*8+j][nt2*256+col], j=0..7.
__global__ void wets2_kernel(const float* __restrict__ We, _Float16* __restrict__ WeTs) {
    int u = blockIdx.x * 256 + threadIdx.x;     // 131072 units
    int col = u & 255;
    int k8  = (u >> 8) & 3;
    int kt  = (u >> 10) & 63;
    int nt  = u >> 16;
    int n  = nt * 256 + col;
    int k0 = kt * 32 + k8 * 8;
    f16x8 h;
#pragma unroll
    for (int j = 0; j < 8; ++j) h[j] = (_Float16)We[(k0 + j) * ATT_ + n];
    *reinterpret_cast<f16x8*>(WeTs + (size_t)u * 8) = h;
}

__global__ void decmap_kernel(const float* __restrict__ dh, const float* __restrict__ Wd,
                              const float* __restrict__ bd, float* __restrict__ dec) {
    int b = blockIdx.x;       // 128
    int a = threadIdx.x;      // 512
    float acc = bd[a];
    const float* dhp = dh + b * DEC_;
#pragma unroll 8
    for (int k = 0; k < DEC_; ++k) acc += dhp[k] * Wd[k * ATT_ + a];
    dec[b * ATT_ + a] = acc;
}

// Fused GEMM (best-measured config, R22/R26): 128x256 tile, BK=32, 256
// threads (4 waves 2x2, wave=64x128). Grid 392 <= 512 slots at 2 blocks/CU
// -> single round. A: reg-cvt staging (2 static sets, 2-ahead) into swizzled
// LDS dbuf. B: global_load_lds DMA 1-ahead into buffer (k+1)%3 (write/read
// distinct mod 3). vmcnt audited: phase k issues [B(k+1) x4, A(k+2) x4];
// writeA's reg-dep drains last-phase A; vmcnt(4) drains exactly B(k+1)
// (issued a full phase earlier) keeping this phase's A loads in flight;
// lgkm-only fences.
__global__ __launch_bounds__(256, 2)
void gemm_score_kernel(const float* __restrict__ enc,
                       const _Float16* __restrict__ WeTs,
                       const float* __restrict__ be,
                       const float* __restrict__ wa,
                       const float* __restrict__ dec,
                       float* __restrict__ scores) {
    __shared__ _Float16 As[2][4096];     // 8KB each
    __shared__ _Float16 Bs[3][8192];     // 16KB each
    __shared__ float red[2][128];

    // XCD swizzle: 392 = 8*49; the 2 ntile-siblings of one mtile share an XCD.
    int bid = blockIdx.x;
    int sid = (bid & 7) * 49 + (bid >> 3);           // bijective on [0,392)
    int mtile = sid >> 1;                            // 0..195
    int nt2   = sid & 1;                             // 0..1

    int tid  = threadIdx.x;
    int lane = tid & 63, wid = tid >> 6;
    int wm = wid >> 1, wn = wid & 1;                 // 2x2, wave = 64x128
    int l15 = lane & 15, lg = lane >> 4;

    // A staging: thread -> rows (tid>>2, +64), c8 = tid&3, 8 fp32 each
    int arowi = tid >> 2;
    int ac8   = tid & 3;
    const float* agA = enc + (size_t)(mtile * 128 + arowi) * ENC_ + ac8 * 8;
    const float* agB = agA + (size_t)64 * ENC_;
    int wa0 = (ac8 * 128 + (arowi ^ (2 * ac8))) * 8;
    int wa1 = wa0 + 64 * 8;

    // B DMA source: WeTs2 units (nt2, kt, p, col=tid); per-kt 8192 halves
    const _Float16* bsrc = WeTs + ((size_t)nt2 * 64 * 1024 + tid) * 8;

    // frag read half-offsets
    int afo = (lg * 128 + wm * 64 + (l15 ^ (2 * lg))) * 8;      // A swizzled
    int bfo = (lg * 256 + wn * 128 + l15) * 8;                  // B linear, +ni*128

    // A staging register sets — statically named (rule #20)
    float4 areg0[4], areg1[4];

    f32x4 acc[4][8];
#pragma unroll
    for (int mi = 0; mi < 4; ++mi)
#pragma unroll
        for (int ni = 0; ni < 8; ++ni) acc[mi][ni] = (f32x4){0.f, 0.f, 0.f, 0.f};

#define DEF_LOADA(S)                                                     \
    auto loadA##S = [&](int kt) {                                        \
        const float* a0 = agA + kt * 32;                                 \
        const float* a1 = agB + kt * 32;                                 \
        areg##S[0] = *reinterpret_cast<const float4*>(a0);               \
        areg##S[1] = *reinterpret_cast<const float4*>(a0 + 4);           \
        areg##S[2] = *reinterpret_cast<const float4*>(a1);               \
        areg##S[3] = *reinterpret_cast<const float4*>(a1 + 4);           \
    }
    DEF_LOADA(0); DEF_LOADA(1);
#undef DEF_LOADA

#define DEF_WRITEA(S)                                                    \
    auto writeA##S = [&](int buf) {                                      \
        _Float16* Ap = As[buf];                                          \
        union { h16x2 h2[4]; f16x8 h8; } cv;                             \
        cv.h2[0] = __builtin_amdgcn_cvt_pkrtz(areg##S[0].x, areg##S[0].y); \
        cv.h2[1] = __builtin_amdgcn_cvt_pkrtz(areg##S[0].z, areg##S[0].w); \
        cv.h2[2] = __builtin_amdgcn_cvt_pkrtz(areg##S[1].x, areg##S[1].y); \
        cv.h2[3] = __builtin_amdgcn_cvt_pkrtz(areg##S[1].z, areg##S[1].w); \
        *reinterpret_cast<f16x8*>(Ap + wa0) = cv.h8;                     \
        cv.h2[0] = __builtin_amdgcn_cvt_pkrtz(areg##S[2].x, areg##S[2].y); \
        cv.h2[1] = __builtin_amdgcn_cvt_pkrtz(areg##S[2].z, areg##S[2].w); \
        cv.h2[2] = __builtin_amdgcn_cvt_pkrtz(areg##S[3].x, areg##S[3].y); \
        cv.h2[3] = __builtin_amdgcn_cvt_pkrtz(areg##S[3].z, areg##S[3].w); \
        *reinterpret_cast<f16x8*>(Ap + wa1) = cv.h8;                     \
    }
    DEF_WRITEA(0); DEF_WRITEA(1);
#undef DEF_WRITEA

    // 4 DMA instructions stage one 32x256 f16 B tile
#define DMAB(BUF, KT)                                                    \
    do {                                                                 \
        const _Float16* s_ = bsrc + (size_t)(KT) * 8192;                 \
        gload16(s_,        &Bs[BUF][(0 * 256 + tid) * 8]);               \
        gload16(s_ + 2048, &Bs[BUF][(1 * 256 + tid) * 8]);               \
        gload16(s_ + 4096, &Bs[BUF][(2 * 256 + tid) * 8]);               \
        gload16(s_ + 6144, &Bs[BUF][(3 * 256 + tid) * 8]);               \
    } while (0)

#define COMPUTE(RA, RB)                                                  \
    do {                                                                 \
        f16x8 af[4], bf[8];                                              \
        _Pragma("unroll")                                                \
        for (int mi = 0; mi < 4; ++mi)                                   \
            af[mi] = *reinterpret_cast<const f16x8*>(&As[RA][afo + mi * 128]); \
        _Pragma("unroll")                                                \
        for (int ni = 0; ni < 8; ++ni)                                   \
            bf[ni] = *reinterpret_cast<const f16x8*>(&Bs[RB][bfo + ni * 128]); \
        __builtin_amdgcn_s_setprio(1);                                   \
        _Pragma("unroll")                                                \
        for (int mi = 0; mi < 4; ++mi)                                   \
            _Pragma("unroll")                                            \
            for (int ni = 0; ni < 8; ++ni)                               \
                acc[mi][ni] = __builtin_amdgcn_mfma_f32_16x16x32_f16(    \
                    af[mi], bf[ni], acc[mi][ni], 0, 0, 0);               \
        __builtin_amdgcn_s_setprio(0);                                   \
    } while (0)

#define PHASE(K, SA, RA, RB, DB, WS)                                     \
    do {                                                                 \
        int ka = (K) + 2 < 64 ? (K) + 2 : 63;                            \
        int kb = (K) + 1 < 64 ? (K) + 1 : 63;                            \
        DMAB(DB, kb);                                                    \
        __builtin_amdgcn_sched_barrier(0);                               \
        loadA##SA(ka);                                                   \
        __builtin_amdgcn_sched_barrier(0);                               \
        COMPUTE(RA, RB);                                                 \
        __builtin_amdgcn_sched_barrier(0);                               \
        writeA##WS(WS);                                                  \
        asm volatile("s_waitcnt vmcnt(4)" ::: "memory");                 \
        __builtin_amdgcn_sched_barrier(0);                               \
        FENCE_LDS_BARRIER();                                             \
    } while (0)

    // prologue: B(0)->Bs0; A tiles 0,1 -> sets 0,1; A(0)->As0; drain all
    DMAB(0, 0);
    __builtin_amdgcn_sched_barrier(0);
    loadA0(0);
    loadA1(1);
    writeA0(0);                      // reg-dep drains A(0),A(1) and B(0)
    asm volatile("s_waitcnt vmcnt(0)" ::: "memory");
    FENCE_LDS_BARRIER();

    for (int k6 = 0; k6 < 10; ++k6) {
        int k = k6 * 6;
        PHASE(k + 0, 0, 0, 0, 1, 1);
        PHASE(k + 1, 1, 1, 1, 2, 0);
        PHASE(k + 2, 0, 0, 2, 0, 1);
        PHASE(k + 3, 1, 1, 0, 1, 0);
        PHASE(k + 4, 0, 0, 1, 2, 1);
        PHASE(k + 5, 1, 1, 2, 0, 0);
    }
    PHASE(60, 0, 0, 0, 1, 1);
    PHASE(61, 1, 1, 1, 2, 0);
    PHASE(62, 0, 0, 2, 0, 1);
    PHASE(63, 1, 1, 0, 1, 0);
#undef PHASE
#undef COMPUTE
#undef DMAB

    // Epilogue: x = acc + be[n] + dec[b][n]; rowsum += tanh(x)*wa[n]
    float rsum[4][4];
#pragma unroll
    for (int mi = 0; mi < 4; ++mi)
#pragma unroll
        for (int j = 0; j < 4; ++j) rsum[mi][j] = 0.f;

    int rb = mtile * 128 + wm * 64;
#pragma unroll
    for (int ni = 0; ni < 8; ++ni) {
        int n = nt2 * 256 + wn * 128 + ni * 16 + l15;
        float wav = wa[n];
        float bev = be[n];
#pragma unroll
        for (int mi = 0; mi < 4; ++mi) {
#pragma unroll
            for (int j = 0; j < 4; ++j) {
                int row = rb + mi * 16 + lg * 4 + j;    // C/D: col=lane&15, row=(lane>>4)*4+reg
                int b = row / L_;
                float x = acc[mi][ni][j] + bev + dec[b * ATT_ + n];
                float e = __expf(2.0f * x);
                float t = 1.0f - 2.0f / (e + 1.0f);     // tanh(x), inf-safe
                rsum[mi][j] += t * wav;
            }
        }
    }
#pragma unroll
    for (int mi = 0; mi < 4; ++mi) {
#pragma unroll
        for (int j = 0; j < 4; ++j) {
            float v = rsum[mi][j];
            v += __shfl_xor(v, 1);
            v += __shfl_xor(v, 2);
            v += __shfl_xor(v, 4);
            v += __shfl_xor(v, 8);
            if (l15 == 0) red[wn][wm * 64 + mi * 16 + lg * 4 + j] = v;
        }
    }
    __syncthreads();
    if (tid < 128)
        scores[(size_t)nt2 * M_ + mtile * 128 + tid] = red[0][tid] + red[1][tid];
}

// softmax over L per batch row; sums the 2 nt2 partials. ba cancels.
__global__ void softmax_kernel(const float* __restrict__ scores, float* __restrict__ alphas) {
    int b = blockIdx.x, t = threadIdx.x;     // 128 blocks x 256 threads
    int lane = t & 63, wid = t >> 6;
    __shared__ float red[4];
    float s = 0.f, val = -1e30f;
    if (t < L_) {
        int r = b * L_ + t;
        s = scores[r] + scores[M_ + r];
        val = s;
    }
    float m = val;
#pragma unroll
    for (int off = 1; off < 64; off <<= 1) m = fmaxf(m, __shfl_xor(m, off));
    if (lane == 0) red[wid] = m;
    __syncthreads();
    m = fmaxf(fmaxf(red[0], red[1]), fmaxf(red[2], red[3]));
    float e = (t < L_) ? __expf(s - m) : 0.f;
    float sum = e;
#pragma unroll
    for (int off = 1; off < 64; off <<= 1) sum += __shfl_xor(sum, off);
    __syncthreads();
    if (lane == 0) red[wid] = sum;
    __syncthreads();
    sum = red[0] + red[1] + red[2] + red[3];
    if (t < L_) alphas[b * L_ + t] = e / sum;
}

// context[b][e] = sum_l alphas[b][l] * enc[b][l][e]  (float4 loads, G13)
__global__ void context_kernel(const float* __restrict__ enc, const float* __restrict__ alphas,
                               float* __restrict__ ctx) {
    int b = blockIdx.x >> 1;                  // 128 b x 2 e-chunks = 256 blocks
    int ec = blockIdx.x & 1;
    int e = ec * 1024 + threadIdx.x * 4;
    const float* ep = enc + (size_t)b * L_ * ENC_ + e;
    const float* ap = alphas + b * L_;
    float a0 = 0.f, a1 = 0.f, a2 = 0.f, a3 = 0.f;
#pragma unroll 4
    for (int l = 0; l < L_; ++l) {
        float a = ap[l];
        float4 v = *reinterpret_cast<const float4*>(ep + (size_t)l * ENC_);
        a0 += a * v.x;
        a1 += a * v.y;
        a2 += a * v.z;
        a3 += a * v.w;
    }
    float4 r; r.x = a0; r.y = a1; r.z = a2; r.w = a3;
    *reinterpret_cast<float4*>(&ctx[b * ENC_ + e]) = r;
}

extern "C" void kernel_launch(void* const* d_in, const int* in_sizes, int n_in,
                              void* d_out, int out_size, void* d_ws, size_t ws_size,
                              hipStream_t stream) {
    const float* enc = (const float*)d_in[0];
    const float* dh  = (const float*)d_in[1];
    const float* We  = (const float*)d_in[2];
    const float* be  = (const float*)d_in[3];
    const float* Wd  = (const float*)d_in[4];
    const float* bd  = (const float*)d_in[5];
    const float* wa  = (const float*)d_in[6];
    // d_in[7] = ba: shifts all scores equally -> cancels in softmax, unused.

    float* out    = (float*)d_out;
    float* ctx    = out;               // [128][2048]
    float* alphas = out + B_ * ENC_;   // [128][196]

    char* ws = (char*)d_ws;
    float*    dec     = (float*)ws;                            // 256 KiB
    _Float16* WeTs2   = (_Float16*)(ws + 262144);              // 2 MiB
    float*    scores  = (float*)(ws + 2359296);                // 2 x 98 KiB

    hipLaunchKernelGGL(wets2_kernel,      dim3(512), dim3(256), 0, stream, We, WeTs2);
    hipLaunchKernelGGL(decmap_kernel,     dim3(128), dim3(512), 0, stream, dh, Wd, bd, dec);
    hipLaunchKernelGGL(gemm_score_kernel, dim3(392), dim3(256), 0, stream, enc, WeTs2, be, wa, dec, scores);
    hipLaunchKernelGGL(softmax_kernel,    dim3(128), dim3(256), 0, stream, scores, alphas);
    hipLaunchKernelGGL(context_kernel,    dim3(256), dim3(256), 0, stream, enc, alphas, ctx);
}